// Round 5
// baseline (75.456 us; speedup 1.0000x reference)
//
#include <hip/hip_runtime.h>
#include <math.h>

// ActELoss, symmetric reformulation, 4 rows/block, two-kernel reduction.
// S = sum_{b,i,j=0..10} exp(-|a0[i]-p0[i+j]|/2)*|a2[i]-p2[i+j]|, p = pad(6 first,5 last)
// Symmetry f(i,m)=f(m,i), f(i,i)=0:
//   S = 2*sum_{k=1..4} sum_i f(i,i+k) + sum_{k=5,6} sum_i f(i,i+k)
//     + sum_{i=1..5}(6-i) f(i,0) + sum_{i=746..748}(i-745) f(i,749)
// plus 0.1 * sum_b ||a0-a2||_2.
// R3 lesson: same-address atomicAdd ~12 ns serialized -> never atomics at this grid.
// R5: 4 rows/block amortizes staging/sync/reduce overhead (4096 -> 1024 blocks).

#define T_LEN 750
#define ROWS  4
#define BLK   256
#define CPT   3            // positions per thread per row; 250 active threads
#define NACT  (T_LEN / CPT)
#define SPAD  756          // staged length: reads up to i0+8 = 755
#define L2E_HALF 0.72134752044f   // 0.5 * log2(e)

__global__ __launch_bounds__(BLK) void actloss_partial(
    const float* __restrict__ a0, const float* __restrict__ a2,
    float* __restrict__ partials)
{
    __shared__ float s0[ROWS][SPAD];
    __shared__ float s2[ROWS][SPAD];

    const int tid = threadIdx.x;
    const size_t base = (size_t)blockIdx.x * ROWS * T_LEN;
    const float* __restrict__ g0 = a0 + base;
    const float* __restrict__ g2 = a2 + base;

    // Stage 4 consecutive rows (3000 contiguous floats per array) as float2.
    // T_LEN=750 is even -> no float2 straddles a row boundary.
    {
        const float2* __restrict__ v0 = (const float2*)g0;
        const float2* __restrict__ v2 = (const float2*)g2;
        for (int k = tid; k < ROWS * 375; k += BLK) {
            const int row  = k / 375;
            const int col2 = 2 * (k - row * 375);
            const float2 x0 = v0[k];
            const float2 x2 = v2[k];
            s0[row][col2]     = x0.x;
            s0[row][col2 + 1] = x0.y;
            s2[row][col2]     = x2.x;
            s2[row][col2 + 1] = x2.y;
        }
        // tail pads [750..755] per row: replicate last element (masked anyway).
        if (tid < ROWS * (SPAD - T_LEN)) {          // 24 threads
            const int row = tid / (SPAD - T_LEN);
            const int c   = tid - row * (SPAD - T_LEN);
            s0[row][T_LEN + c] = g0[row * T_LEN + T_LEN - 1];
            s2[row][T_LEN + c] = g2[row * T_LEN + T_LEN - 1];
        }
    }
    __syncthreads();

    float loss1 = 0.0f;            // weight-1 terms (k=5,6 and edge extras)
    float loss2 = 0.0f;            // weight-2 terms (k=1..4)
    float sq[ROWS] = {0.0f, 0.0f, 0.0f, 0.0f};

    if (tid < NACT) {
        const int i0 = tid * CPT;
#pragma unroll
        for (int r = 0; r < ROWS; ++r) {
            float r0[CPT + 6], r2[CPT + 6];
#pragma unroll
            for (int k = 0; k < CPT + 6; ++k) {
                r0[k] = s0[r][i0 + k];
                r2[k] = s2[r][i0 + k];
            }
#pragma unroll
            for (int ci = 0; ci < CPT; ++ci) {
                const float c0 = r0[ci];
                const float c2 = r2[ci];
#pragma unroll
                for (int k = 1; k <= 6; ++k) {
                    const float wv  = __builtin_amdgcn_exp2f(
                                          -L2E_HALF * fabsf(c0 - r0[ci + k]));
                    float ad2 = fabsf(c2 - r2[ci + k]);
                    ad2 = (i0 + ci + k < T_LEN) ? ad2 : 0.0f;  // out-of-range pairs
                    if (k <= 4) loss2 = fmaf(wv, ad2, loss2);
                    else        loss1 = fmaf(wv, ad2, loss1);
                }
                const float d = c0 - c2;
                sq[r] = fmaf(d, d, sq[r]);
            }
        }
    } else if (tid < NACT + ROWS) {
        // clamp edge extras (8 terms) for row r
        const int r = tid - NACT;
#pragma unroll
        for (int i = 1; i <= 5; ++i) {
            const float wv = __builtin_amdgcn_exp2f(-L2E_HALF * fabsf(s0[r][i] - s0[r][0]));
            loss1 = fmaf(wv * (float)(6 - i), fabsf(s2[r][i] - s2[r][0]), loss1);
        }
#pragma unroll
        for (int i = 746; i <= 748; ++i) {
            const float wv = __builtin_amdgcn_exp2f(-L2E_HALF * fabsf(s0[r][i] - s0[r][T_LEN - 1]));
            loss1 = fmaf(wv * (float)(i - 745), fabsf(s2[r][i] - s2[r][T_LEN - 1]), loss1);
        }
    }

    float loss = fmaf(2.0f, loss2, loss1);

    // wave64 shuffle reduce: 5 chains (loss, sq[0..3])
#pragma unroll
    for (int off = 32; off > 0; off >>= 1) {
        loss += __shfl_down(loss, off, 64);
#pragma unroll
        for (int r = 0; r < ROWS; ++r) sq[r] += __shfl_down(sq[r], off, 64);
    }
    __shared__ float rl[BLK / 64];
    __shared__ float rs[BLK / 64][ROWS];
    const int wid  = tid >> 6;
    const int lane = tid & 63;
    if (lane == 0) {
        rl[wid] = loss;
#pragma unroll
        for (int r = 0; r < ROWS; ++r) rs[wid][r] = sq[r];
    }
    __syncthreads();
    if (tid == 0) {
        float L = 0.0f;
        float S[ROWS] = {0.0f, 0.0f, 0.0f, 0.0f};
#pragma unroll
        for (int w = 0; w < BLK / 64; ++w) {
            L += rl[w];
#pragma unroll
            for (int r = 0; r < ROWS; ++r) S[r] += rs[w][r];
        }
        float reg = 0.0f;
#pragma unroll
        for (int r = 0; r < ROWS; ++r) reg += sqrtf(S[r]);
        partials[blockIdx.x] = L + 0.1f * reg;
    }
}

__global__ __launch_bounds__(BLK) void actloss_final(
    const float* __restrict__ partials, int n4, float* __restrict__ out)
{
    const float4* __restrict__ p4 = (const float4*)partials;
    float v = 0.0f;
    for (int k = threadIdx.x; k < n4; k += BLK) {
        const float4 x = p4[k];
        v += (x.x + x.y) + (x.z + x.w);
    }
#pragma unroll
    for (int off = 32; off > 0; off >>= 1) v += __shfl_down(v, off, 64);
    __shared__ float r[BLK / 64];
    if ((threadIdx.x & 63) == 0) r[threadIdx.x >> 6] = v;
    __syncthreads();
    if (threadIdx.x == 0) {
        float s = 0.0f;
#pragma unroll
        for (int w = 0; w < BLK / 64; ++w) s += r[w];
        out[0] = s;
    }
}

extern "C" void kernel_launch(void* const* d_in, const int* in_sizes, int n_in,
                              void* d_out, int out_size, void* d_ws, size_t ws_size,
                              hipStream_t stream)
{
    const float* a0 = (const float*)d_in[0];
    const float* a2 = (const float*)d_in[1];
    float* out      = (float*)d_out;
    float* partials = (float*)d_ws;                  // B/ROWS floats, overwritten
    const int B = in_sizes[0] / T_LEN;               // 4096
    const int nblk = B / ROWS;                       // 1024

    actloss_partial<<<nblk, BLK, 0, stream>>>(a0, a2, partials);
    actloss_final<<<1, BLK, 0, stream>>>(partials, nblk / 4, out);
}